// Round 5
// baseline (1304.480 us; speedup 1.0000x reference)
//
#include <hip/hip_runtime.h>

// Problem constants
#define BB 16
#define HH 128
#define WW 128
#define CC 256
#define MM (BB*HH*WW)     // 262144
#define KK 512            // 2*CC
#define NT 8              // K-tiles of BK=64

typedef __attribute__((ext_vector_type(8))) short s16x8;
typedef __attribute__((ext_vector_type(4))) float f32x4;

__device__ static inline unsigned short f2bf(float x) {
    union { float f; unsigned u; } v; v.f = x;
    unsigned r = v.u + 0x7fffu + ((v.u >> 16) & 1u);  // round-nearest-even
    return (unsigned short)(r >> 16);
}

__device__ static inline void gload_lds16(const void* g, void* l) {
    __builtin_amdgcn_global_load_lds(
        (const __attribute__((address_space(1))) void*)g,
        (__attribute__((address_space(3))) void*)l,
        16, 0, 0);
}

// Scan 128 steps of running max over float4 lanes, forced 8-deep MLP.
__device__ __forceinline__ void scan_row(const float4* __restrict__ src, size_t sstride,
                                         unsigned short* __restrict__ dst, size_t dstride,
                                         bool do_sync) {
    float4 ba0,ba1,ba2,ba3,ba4,ba5,ba6,ba7;
    float4 bb0,bb1,bb2,bb3,bb4,bb5,bb6,bb7;
    const float4* ps = src;
    ba0=ps[0*sstride]; ba1=ps[1*sstride]; ba2=ps[2*sstride]; ba3=ps[3*sstride];
    ba4=ps[4*sstride]; ba5=ps[5*sstride]; ba6=ps[6*sstride]; ba7=ps[7*sstride];
    __builtin_amdgcn_sched_group_barrier(0x20, 8, 0);   // pin: 8 vmem reads issued
    ps += 8 * sstride;
    float4 run = make_float4(-3.4e38f, -3.4e38f, -3.4e38f, -3.4e38f);
    unsigned short* pd = dst;

#define CONSUME(v, stepj)                                            \
    do {                                                             \
        run.x = fmaxf(run.x, (v).x); run.y = fmaxf(run.y, (v).y);    \
        run.z = fmaxf(run.z, (v).z); run.w = fmaxf(run.w, (v).w);    \
        ushort4 o;                                                   \
        o.x = f2bf(run.x); o.y = f2bf(run.y);                        \
        o.z = f2bf(run.z); o.w = f2bf(run.w);                        \
        *(ushort4*)(pd + (size_t)(stepj) * dstride) = o;             \
    } while (0)

    for (int g = 0; g < 8; ++g) {   // 2 groups of 8 steps per iteration
        bb0=ps[0*sstride]; bb1=ps[1*sstride]; bb2=ps[2*sstride]; bb3=ps[3*sstride];
        bb4=ps[4*sstride]; bb5=ps[5*sstride]; bb6=ps[6*sstride]; bb7=ps[7*sstride];
        __builtin_amdgcn_sched_group_barrier(0x20, 8, 0);
        ps += 8 * sstride;
        CONSUME(ba0,0); CONSUME(ba1,1); CONSUME(ba2,2); CONSUME(ba3,3);
        CONSUME(ba4,4); CONSUME(ba5,5); CONSUME(ba6,6); CONSUME(ba7,7);
        pd += 8 * dstride;
        if (do_sync) __syncthreads();
        if (g < 7) {
            ba0=ps[0*sstride]; ba1=ps[1*sstride]; ba2=ps[2*sstride]; ba3=ps[3*sstride];
            ba4=ps[4*sstride]; ba5=ps[5*sstride]; ba6=ps[6*sstride]; ba7=ps[7*sstride];
            __builtin_amdgcn_sched_group_barrier(0x20, 8, 0);
            ps += 8 * sstride;
        }
        CONSUME(bb0,0); CONSUME(bb1,1); CONSUME(bb2,2); CONSUME(bb3,3);
        CONSUME(bb4,4); CONSUME(bb5,5); CONSUME(bb6,6); CONSUME(bb7,7);
        pd += 8 * dstride;
        if (do_sync) __syncthreads();
    }
#undef CONSUME
}

// ---- w-scan (+ W conversion tail blocks). blocks [0,512): 4 (b,h) rows each
// (one per wave); blocks [512,544): Wf f32 -> Wt bf16 k-grouped.
__global__ __launch_bounds__(256) void scan_w_kernel(const float* __restrict__ grid,
                                                     const float* __restrict__ Wf,
                                                     unsigned short* __restrict__ Ax,
                                                     unsigned short* __restrict__ Wt) {
    const int bid = blockIdx.x;
    const int t   = threadIdx.x;
    if (bid < 512) {
        const int bh = bid * 4 + (t >> 6);   // row (b*128+h)
        const int c4 = t & 63;
        const float4* src = (const float4*)(grid + (size_t)bh * WW * CC) + c4;
        unsigned short* dst = Ax + (size_t)bh * WW * CC + c4 * 4;   // row stride 256
        scan_row(src, CC / 4, dst, CC, false);
    } else {
        // W[512,256] f32 -> Wt bf16: Wt[(k/8)*256 + n][k%8]
        const int base = (bid - 512) * 4096;
        #pragma unroll 4
        for (int j = 0; j < 16; ++j) {
            const int i = base + j * 256 + t;   // 0..131071
            const int k = i >> 8, n = i & 255;
            Wt[(((size_t)(k >> 3) * 256 + n) << 3) + (k & 7)] = f2bf(Wf[i]);
        }
    }
}

// ---- h-scan: 256 blocks x 512 threads; block = (b, 8 w-columns), wave per w.
__global__ __launch_bounds__(512) void scan_h_kernel(const float* __restrict__ grid,
                                                     unsigned short* __restrict__ Ay) {
    const int bid = blockIdx.x;
    const int t   = threadIdx.x;
    const int b   = bid >> 4;
    const int w   = (bid & 15) * 8 + (t >> 6);
    const int c4  = t & 63;
    const float4* src = (const float4*)(grid + ((size_t)b * HH * WW + w) * CC) + c4;
    unsigned short* dst = Ay + ((size_t)b * HH * WW + w) * CC + c4 * 4;  // h=0 row
    scan_row(src, (size_t)WW * CC / 4, dst, (size_t)WW * CC, true);
}

// ---- GEMM: out[M,256] = [Ax|Ay][M,512](bf16) @ W(bf16) + bias, f32 out.
// BM=128, BN=256 (full N), BK=64. 512 threads = 8 waves (2 wm x 4 wn),
// wave tile 64x64. A-only LDS ring-of-3 (48 KB -> 3 blocks/CU, 75% occ);
// B fragments straight from L2-resident Wt into double-buffered registers.
// Counted vmcnt(2) per tile keeps next A-tile in flight across the barrier.
__global__ __launch_bounds__(512, 6) void gemm_kernel(const unsigned short* __restrict__ Axg,
                                                      const unsigned short* __restrict__ Ayg,
                                                      const unsigned short* __restrict__ Wt,
                                                      const float* __restrict__ bias,
                                                      float* __restrict__ out) {
    __shared__ __align__(16) unsigned char lds[49152];   // 3 x 16 KB A tiles

    const int t    = threadIdx.x;
    const int lane = t & 63;
    const int wid  = t >> 6;
    const int wm   = wid >> 2;          // 0..1 -> rows wm*64..+63
    const int wn   = wid & 3;           // 0..3 -> cols wn*64..+63
    const size_t m0 = (size_t)blockIdx.x * 128;

    const f32x4 fzero = {0.f, 0.f, 0.f, 0.f};
    f32x4 acc[4][4];
    #pragma unroll
    for (int i = 0; i < 4; ++i)
        #pragma unroll
        for (int j = 0; j < 4; ++j) acc[i][j] = fzero;

    // A fragment LDS byte offsets (q=0); q=1: ^64
    int aoff[4];
    #pragma unroll
    for (int fm = 0; fm < 4; ++fm) {
        const int row = wm * 64 + fm * 16 + (lane & 15);
        const int pc  = (lane >> 4) ^ (row & 7);
        aoff[fm] = row * 128 + pc * 16;
    }

    // B: Wt viewed as s16x8[g*256+n]; per-lane base
    const s16x8* Wv = (const s16x8*)Wt;
    const int bbase = (lane >> 4) * 256 + wn * 64 + (lane & 15);

    // A staging: tile tt (compile-time) -> ring buffer tt%3
    #define STAGE_A(tt, i)                                                        \
        do {                                                                      \
            const int f_   = t + (i) * 512;          /* 0..1023 */                \
            const int row_ = f_ >> 3;                                             \
            const int sc_  = (f_ & 7) ^ (row_ & 7);                               \
            const unsigned short* bp_ = ((tt) < 4) ? Axg : Ayg;                   \
            gload_lds16(bp_ + (m0 + row_) * (size_t)CC + ((tt) & 3) * 64 + sc_ * 8,\
                        lds + ((tt) % 3) * 16384 + f_ * 16);                      \
        } while (0)

    s16x8 bset[2][8];

    // prologue: A0, B0, A1 (order pinned) -> [A0:2][B0:8][A1:2]; vmcnt(2)
    STAGE_A(0, 0); STAGE_A(0, 1);
    __builtin_amdgcn_sched_barrier(0);
    #pragma unroll
    for (int fn = 0; fn < 4; ++fn) {
        bset[0][fn]     = Wv[bbase + fn * 16];
        bset[0][4 + fn] = Wv[bbase + 1024 + fn * 16];
    }
    __builtin_amdgcn_sched_barrier(0);
    STAGE_A(1, 0); STAGE_A(1, 1);
    __builtin_amdgcn_sched_barrier(0);
    asm volatile("s_waitcnt vmcnt(2)" ::: "memory");
    __builtin_amdgcn_s_barrier();

    #pragma unroll
    for (int tt = 0; tt < NT; ++tt) {
        const unsigned char* Ac = lds + (tt % 3) * 16384;
        // issue next-tile B into the alternate register set (oldest-first order)
        if (tt + 1 < NT) {
            #pragma unroll
            for (int fn = 0; fn < 4; ++fn) {
                bset[(tt + 1) & 1][fn]     = Wv[bbase + (tt + 1) * 2048 + fn * 16];
                bset[(tt + 1) & 1][4 + fn] = Wv[bbase + (tt + 1) * 2048 + 1024 + fn * 16];
            }
        }
        __builtin_amdgcn_sched_barrier(0);
        if (tt + 2 < NT) { STAGE_A(tt + 2, 0); STAGE_A(tt + 2, 1); }
        __builtin_amdgcn_sched_barrier(0);

        __builtin_amdgcn_s_setprio(1);
        #pragma unroll
        for (int q = 0; q < 2; ++q) {
            s16x8 af[4];
            #pragma unroll
            for (int fm = 0; fm < 4; ++fm)
                af[fm] = *(const s16x8*)(Ac + (aoff[fm] ^ (q * 64)));
            #pragma unroll
            for (int fm = 0; fm < 4; ++fm)
                #pragma unroll
                for (int fn = 0; fn < 4; ++fn)
                    acc[fm][fn] = __builtin_amdgcn_mfma_f32_16x16x32_bf16(
                        af[fm], bset[tt & 1][q * 4 + fn], acc[fm][fn], 0, 0, 0);
        }
        __builtin_amdgcn_s_setprio(0);

        // gate: outstanding = [A(tt+1):2][B(tt+1):8][A(tt+2):2]
        if (tt < NT - 2) {
            asm volatile("s_waitcnt vmcnt(2)" ::: "memory");
            __builtin_amdgcn_s_barrier();
        } else if (tt == NT - 2) {
            asm volatile("s_waitcnt vmcnt(0)" ::: "memory");
            __builtin_amdgcn_s_barrier();
        }
    }
    #undef STAGE_A

    // epilogue: C/D layout col = lane&15, row = (lane>>4)*4 + reg   [verified r0]
    #pragma unroll
    for (int fn = 0; fn < 4; ++fn) {
        const int col = wn * 64 + fn * 16 + (lane & 15);
        const float bb = bias[col];
        #pragma unroll
        for (int fm = 0; fm < 4; ++fm) {
            const int rbase = wm * 64 + fm * 16 + ((lane >> 4) << 2);
            #pragma unroll
            for (int r = 0; r < 4; ++r) {
                out[(m0 + rbase + r) * (size_t)CC + col] = acc[fm][fn][r] + bb;
            }
        }
    }
}

extern "C" void kernel_launch(void* const* d_in, const int* in_sizes, int n_in,
                              void* d_out, int out_size, void* d_ws, size_t ws_size,
                              hipStream_t stream) {
    const float* grid = (const float*)d_in[0];
    const float* Wf   = (const float*)d_in[1];
    const float* bias = (const float*)d_in[2];
    float* out        = (float*)d_out;

    // workspace: Ax bf16 [M,256] = 128 MB, Ay bf16 [M,256] = 128 MB, Wt 256 KB
    unsigned short* Ax = (unsigned short*)d_ws;
    unsigned short* Ay = (unsigned short*)((char*)d_ws + (size_t)134217728);
    unsigned short* Wt = (unsigned short*)((char*)d_ws + (size_t)268435456);

    scan_w_kernel<<<544, 256, 0, stream>>>(grid, Wf, Ax, Wt);
    scan_h_kernel<<<256, 512, 0, stream>>>(grid, Ay);
    gemm_kernel<<<2048, 512, 0, stream>>>(Ax, Ay, Wt, bias, out);
}

// Round 6
// 298.893 us; speedup vs baseline: 4.3644x; 4.3644x over previous
//
#include <hip/hip_runtime.h>

// Problem constants
#define BB 16
#define HH 128
#define WW 128
#define CC 256
#define MM (BB*HH*WW)     // 262144
#define KK 512            // 2*CC
#define NT 8              // K-tiles of BK=64

typedef __attribute__((ext_vector_type(8))) short s16x8;
typedef __attribute__((ext_vector_type(4))) float f32x4;

__device__ static inline unsigned short f2bf(float x) {
    union { float f; unsigned u; } v; v.f = x;
    unsigned r = v.u + 0x7fffu + ((v.u >> 16) & 1u);  // round-nearest-even
    return (unsigned short)(r >> 16);
}

__device__ static inline void gload_lds16(const void* g, void* l) {
    __builtin_amdgcn_global_load_lds(
        (const __attribute__((address_space(1))) void*)g,
        (__attribute__((address_space(3))) void*)l,
        16, 0, 0);
}

// Scan 128 steps of running max over float4 lanes, forced 8-deep MLP.
__device__ __forceinline__ void scan_row(const float4* __restrict__ src, size_t sstride,
                                         unsigned short* __restrict__ dst, size_t dstride,
                                         bool do_sync) {
    float4 ba0,ba1,ba2,ba3,ba4,ba5,ba6,ba7;
    float4 bb0,bb1,bb2,bb3,bb4,bb5,bb6,bb7;
    const float4* ps = src;
    ba0=ps[0*sstride]; ba1=ps[1*sstride]; ba2=ps[2*sstride]; ba3=ps[3*sstride];
    ba4=ps[4*sstride]; ba5=ps[5*sstride]; ba6=ps[6*sstride]; ba7=ps[7*sstride];
    __builtin_amdgcn_sched_group_barrier(0x20, 8, 0);   // pin: 8 vmem reads issued
    ps += 8 * sstride;
    float4 run = make_float4(-3.4e38f, -3.4e38f, -3.4e38f, -3.4e38f);
    unsigned short* pd = dst;

#define CONSUME(v, stepj)                                            \
    do {                                                             \
        run.x = fmaxf(run.x, (v).x); run.y = fmaxf(run.y, (v).y);    \
        run.z = fmaxf(run.z, (v).z); run.w = fmaxf(run.w, (v).w);    \
        ushort4 o;                                                   \
        o.x = f2bf(run.x); o.y = f2bf(run.y);                        \
        o.z = f2bf(run.z); o.w = f2bf(run.w);                        \
        *(ushort4*)(pd + (size_t)(stepj) * dstride) = o;             \
    } while (0)

    for (int g = 0; g < 8; ++g) {   // 2 groups of 8 steps per iteration
        bb0=ps[0*sstride]; bb1=ps[1*sstride]; bb2=ps[2*sstride]; bb3=ps[3*sstride];
        bb4=ps[4*sstride]; bb5=ps[5*sstride]; bb6=ps[6*sstride]; bb7=ps[7*sstride];
        __builtin_amdgcn_sched_group_barrier(0x20, 8, 0);
        ps += 8 * sstride;
        CONSUME(ba0,0); CONSUME(ba1,1); CONSUME(ba2,2); CONSUME(ba3,3);
        CONSUME(ba4,4); CONSUME(ba5,5); CONSUME(ba6,6); CONSUME(ba7,7);
        pd += 8 * dstride;
        if (do_sync) __syncthreads();
        if (g < 7) {
            ba0=ps[0*sstride]; ba1=ps[1*sstride]; ba2=ps[2*sstride]; ba3=ps[3*sstride];
            ba4=ps[4*sstride]; ba5=ps[5*sstride]; ba6=ps[6*sstride]; ba7=ps[7*sstride];
            __builtin_amdgcn_sched_group_barrier(0x20, 8, 0);
            ps += 8 * sstride;
        }
        CONSUME(bb0,0); CONSUME(bb1,1); CONSUME(bb2,2); CONSUME(bb3,3);
        CONSUME(bb4,4); CONSUME(bb5,5); CONSUME(bb6,6); CONSUME(bb7,7);
        pd += 8 * dstride;
        if (do_sync) __syncthreads();
    }
#undef CONSUME
}

// ---- w-scan (+ W conversion tail blocks). blocks [0,512): 4 (b,h) rows each
// (one per wave); blocks [512,544): Wf f32 -> Wt bf16 k-grouped.
__global__ __launch_bounds__(256) void scan_w_kernel(const float* __restrict__ grid,
                                                     const float* __restrict__ Wf,
                                                     unsigned short* __restrict__ Ax,
                                                     unsigned short* __restrict__ Wt) {
    const int bid = blockIdx.x;
    const int t   = threadIdx.x;
    if (bid < 512) {
        const int bh = bid * 4 + (t >> 6);   // row (b*128+h)
        const int c4 = t & 63;
        const float4* src = (const float4*)(grid + (size_t)bh * WW * CC) + c4;
        unsigned short* dst = Ax + (size_t)bh * WW * CC + c4 * 4;   // row stride 256
        scan_row(src, CC / 4, dst, CC, false);
    } else {
        // W[512,256] f32 -> Wt bf16: Wt[(k/8)*256 + n][k%8]
        const int base = (bid - 512) * 4096;
        #pragma unroll 4
        for (int j = 0; j < 16; ++j) {
            const int i = base + j * 256 + t;   // 0..131071
            const int k = i >> 8, n = i & 255;
            Wt[(((size_t)(k >> 3) * 256 + n) << 3) + (k & 7)] = f2bf(Wf[i]);
        }
    }
}

// ---- h-scan: 256 blocks x 512 threads; block = (b, 8 w-columns), wave per w.
__global__ __launch_bounds__(512) void scan_h_kernel(const float* __restrict__ grid,
                                                     unsigned short* __restrict__ Ay) {
    const int bid = blockIdx.x;
    const int t   = threadIdx.x;
    const int b   = bid >> 4;
    const int w   = (bid & 15) * 8 + (t >> 6);
    const int c4  = t & 63;
    const float4* src = (const float4*)(grid + ((size_t)b * HH * WW + w) * CC) + c4;
    unsigned short* dst = Ay + ((size_t)b * HH * WW + w) * CC + c4 * 4;  // h=0 row
    scan_row(src, (size_t)WW * CC / 4, dst, (size_t)WW * CC, true);
}

// ---- GEMM: out[M,256] = [Ax|Ay][M,512](bf16) @ W(bf16) + bias, f32 out.
// BM=128, BN=128, BK=64. 256 threads = 4 waves (2 wm x 2 wn), wave 64x64.
// A-only LDS ring-of-3 (48 KB). B straight from L2-resident Wt into
// double-buffered registers. Register budget: acc 64 + bset 64 + ~35 ->
// launch_bounds(256,3) caps at ~170 VGPR -> 3 blocks/CU, no spill.
// Sibling N-blocks (same m0) mapped to the same XCD for A L2 reuse.
__global__ __launch_bounds__(256, 3) void gemm_kernel(const unsigned short* __restrict__ Axg,
                                                      const unsigned short* __restrict__ Ayg,
                                                      const unsigned short* __restrict__ Wt,
                                                      const float* __restrict__ bias,
                                                      float* __restrict__ out) {
    __shared__ __align__(16) unsigned char lds[49152];   // 3 x 16 KB A tiles

    const int t    = threadIdx.x;
    const int lane = t & 63;
    const int wid  = t >> 6;            // 0..3
    const int wm   = wid >> 1;          // 0..1 -> rows wm*64..+63
    const int wn   = wid & 1;           // 0..1 -> cols wn*64..+63 (of 128)
    // XCD-pairing remap: HW maps bid%8 -> XCD. Give each XCD contiguous
    // M-tile pairs so the two N-siblings of an M-tile share L2-resident A.
    const int bid  = blockIdx.x;        // 0..4095
    const int xcd  = bid & 7;
    const int j    = bid >> 3;          // 0..511 within XCD
    const int mt   = xcd * 256 + (j >> 1);   // 0..2047
    const size_t m0 = (size_t)mt * 128;
    const int n0    = (j & 1) * 128;

    const f32x4 fzero = {0.f, 0.f, 0.f, 0.f};
    f32x4 acc[4][4];
    #pragma unroll
    for (int i = 0; i < 4; ++i)
        #pragma unroll
        for (int jj = 0; jj < 4; ++jj) acc[i][jj] = fzero;

    // A fragment LDS byte offsets (q=0); q=1: ^64
    int aoff[4];
    #pragma unroll
    for (int fm = 0; fm < 4; ++fm) {
        const int row = wm * 64 + fm * 16 + (lane & 15);
        const int pc  = (lane >> 4) ^ (row & 7);
        aoff[fm] = row * 128 + pc * 16;
    }

    // B: Wt viewed as s16x8[g*256 + n]; per-lane base (g = lane>>4 part)
    const s16x8* Wv = (const s16x8*)Wt;
    const int bb0 = (lane >> 4) * 256 + n0 + wn * 64 + (lane & 15);

    // A staging: tile tt (compile-time) -> ring buffer tt%3; 4 loads/thread
    #define STAGE_A(tt)                                                            \
        do {                                                                       \
            _Pragma("unroll")                                                      \
            for (int i_ = 0; i_ < 4; ++i_) {                                       \
                const int f_   = t + i_ * 256;          /* 0..1023 */              \
                const int row_ = f_ >> 3;                                          \
                const int sc_  = (f_ & 7) ^ (row_ & 7);                            \
                const unsigned short* bp_ = ((tt) < 4) ? Axg : Ayg;                \
                gload_lds16(bp_ + (m0 + row_) * (size_t)CC + ((tt) & 3) * 64       \
                                + sc_ * 8,                                         \
                            lds + ((tt) % 3) * 16384 + f_ * 16);                   \
            }                                                                      \
        } while (0)

    s16x8 bset[2][8];

    // prologue: A0(4), B0(8), A1(4); wait A0 -> vmcnt(12)
    STAGE_A(0);
    __builtin_amdgcn_sched_barrier(0);
    #pragma unroll
    for (int q = 0; q < 2; ++q)
        #pragma unroll
        for (int fn = 0; fn < 4; ++fn)
            bset[0][q * 4 + fn] = Wv[bb0 + q * 1024 + fn * 16];
    __builtin_amdgcn_sched_barrier(0);
    STAGE_A(1);
    __builtin_amdgcn_sched_barrier(0);
    asm volatile("s_waitcnt vmcnt(12)" ::: "memory");
    __builtin_amdgcn_s_barrier();

    #pragma unroll
    for (int tt = 0; tt < NT; ++tt) {
        const unsigned char* Ac = lds + (tt % 3) * 16384;
        // issue next-tile B into the alternate register set
        if (tt + 1 < NT) {
            #pragma unroll
            for (int q = 0; q < 2; ++q)
                #pragma unroll
                for (int fn = 0; fn < 4; ++fn)
                    bset[(tt + 1) & 1][q * 4 + fn] =
                        Wv[bb0 + (tt + 1) * 2048 + q * 1024 + fn * 16];
        }
        __builtin_amdgcn_sched_barrier(0);
        if (tt + 2 < NT) STAGE_A(tt + 2);
        __builtin_amdgcn_sched_barrier(0);

        __builtin_amdgcn_s_setprio(1);
        #pragma unroll
        for (int q = 0; q < 2; ++q) {
            s16x8 af[4];
            #pragma unroll
            for (int fm = 0; fm < 4; ++fm)
                af[fm] = *(const s16x8*)(Ac + (aoff[fm] ^ (q * 64)));
            #pragma unroll
            for (int fm = 0; fm < 4; ++fm)
                #pragma unroll
                for (int fn = 0; fn < 4; ++fn)
                    acc[fm][fn] = __builtin_amdgcn_mfma_f32_16x16x32_bf16(
                        af[fm], bset[tt & 1][q * 4 + fn], acc[fm][fn], 0, 0, 0);
        }
        __builtin_amdgcn_s_setprio(0);

        // gate: outstanding = [A(tt+1):4][B(tt+1):8][A(tt+2):4] -> drain A(tt+1)
        if (tt < NT - 2) {
            asm volatile("s_waitcnt vmcnt(12)" ::: "memory");
            __builtin_amdgcn_s_barrier();
        } else if (tt == NT - 2) {
            asm volatile("s_waitcnt vmcnt(8)" ::: "memory");
            __builtin_amdgcn_s_barrier();
        }
    }
    #undef STAGE_A

    // epilogue: C/D layout col = lane&15, row = (lane>>4)*4 + reg   [verified r0]
    #pragma unroll
    for (int fn = 0; fn < 4; ++fn) {
        const int col = n0 + wn * 64 + fn * 16 + (lane & 15);
        const float bb = bias[col];
        #pragma unroll
        for (int fm = 0; fm < 4; ++fm) {
            const int rbase = wm * 64 + fm * 16 + ((lane >> 4) << 2);
            #pragma unroll
            for (int r = 0; r < 4; ++r) {
                out[(m0 + rbase + r) * (size_t)CC + col] = acc[fm][fn][r] + bb;
            }
        }
    }
}

extern "C" void kernel_launch(void* const* d_in, const int* in_sizes, int n_in,
                              void* d_out, int out_size, void* d_ws, size_t ws_size,
                              hipStream_t stream) {
    const float* grid = (const float*)d_in[0];
    const float* Wf   = (const float*)d_in[1];
    const float* bias = (const float*)d_in[2];
    float* out        = (float*)d_out;

    // workspace: Ax bf16 [M,256] = 128 MB, Ay bf16 [M,256] = 128 MB, Wt 256 KB
    unsigned short* Ax = (unsigned short*)d_ws;
    unsigned short* Ay = (unsigned short*)((char*)d_ws + (size_t)134217728);
    unsigned short* Wt = (unsigned short*)((char*)d_ws + (size_t)268435456);

    scan_w_kernel<<<544, 256, 0, stream>>>(grid, Wf, Ax, Wt);
    scan_h_kernel<<<256, 512, 0, stream>>>(grid, Ay);
    gemm_kernel<<<4096, 256, 0, stream>>>(Ax, Ay, Wt, bias, out);
}